// Round 5
// baseline (2722.582 us; speedup 1.0000x reference)
//
#include <hip/hip_runtime.h>
#include <hip/hip_bf16.h>
#include <cstdint>

typedef unsigned short u16;
typedef __bf16 bf16x8 __attribute__((ext_vector_type(8)));
typedef float f32x4 __attribute__((ext_vector_type(4)));
typedef unsigned short us8 __attribute__((ext_vector_type(8)));

#define AS1 __attribute__((address_space(1)))
#define AS3 __attribute__((address_space(3)))

__device__ __forceinline__ float b2f(u16 u) {
    union { float f; uint32_t i; } c; c.i = ((uint32_t)u) << 16; return c.f;
}
__device__ __forceinline__ u16 f2b(float f) {
    union { float f; uint32_t i; } c; c.f = f;
    return (u16)((c.i + 0x7fffu + ((c.i >> 16) & 1u)) >> 16);
}

#define BM 256
#define BN 256
#define BK 64
#define GK 1024
#define GN 1024
#define NKT (GK / BK)   // 16 K-tiles

#define BAR asm volatile("s_barrier" ::: "memory")

// One GEMM op descriptor (one op per dispatch — merging heterogeneous ops
// thrashed L2/L3 and doubled every merged dispatch; measured round 4).
// C[b] (MxN row-major) = scale*(A[b] @ B[b]^T) [+bias(row|col)] [+r1u⊗r1v] [+res bf16]
// transp=1 (u16 out only): store C^T instead, with fp32 residual resF (natural layout).
struct GOp {
    const u16* A; const u16* B; void* C;
    long long sA, sB, sC, sR;
    const float* bias; const u16* res; const float* r1u; const float* r1v;
    const float* resF;
    float scale;
    int biasMode;   // 0 none, 1 row, 2 col
    int transp;
};

// 256x256 tile, BK=64, 8 waves (2Mx4N), 512 threads, 128 KiB LDS (2 bufs).
// 8-phase schedule with counted vmcnt; raw s_barrier keeps staging loads in
// flight across barriers. LDS 16B chunks XOR-swizzled.
template <typename OutT>
__global__ __launch_bounds__(512, 2) void gemm_nt(GOp o)
{
    __shared__ __align__(16) char smem[131072];

    const int t = threadIdx.x;
    // XCD-aware bijective swizzle: 512 blocks, 64 consecutive per XCD
    const int orig = blockIdx.x;
    const int id2 = (orig & 7) * 64 + (orig >> 3);
    const int bz = id2 >> 4;           // batch 0..31
    const int by = (id2 >> 2) & 3;     // M tile 0..3
    const int bx = id2 & 3;            // N tile 0..3

    const u16* Ab = o.A + (size_t)bz * o.sA + (size_t)(by * BM) * GK;
    const u16* Bb = o.B + (size_t)bz * o.sB + (size_t)(bx * BN) * GK;

    const int wave = t >> 6, lane = t & 63;
    const int l16 = lane & 15, quad = lane >> 4;
    const int wr = wave >> 2;      // 0..1  (M: 128 rows each)
    const int wc = wave & 3;       // 0..3  (N: 64 cols each)
    const int bq = l16 & 7;

    f32x4 acc[8][4] = {};

    int geoff[2], ldoff[2];
    #pragma unroll
    for (int i = 0; i < 2; ++i) {
        const int c = t + 512 * i;
        const int r = c >> 3, js = c & 7;
        geoff[i] = r * GK + (js ^ (r & 7)) * 8;
        ldoff[i] = c * 16;
    }

    #define STG_A(tile, h)                                                               \
        _Pragma("unroll")                                                                \
        for (int i = 0; i < 2; ++i)                                                      \
            __builtin_amdgcn_global_load_lds(                                            \
                (AS1 const void*)(Ab + (size_t)(h) * 128 * GK + geoff[i] + (tile) * BK), \
                (AS3 void*)(smem + ((tile) & 1) * 65536 + (h) * 16384 + ldoff[i]),       \
                16, 0, 0);
    #define STG_B(tile, h)                                                               \
        _Pragma("unroll")                                                                \
        for (int i = 0; i < 2; ++i)                                                      \
            __builtin_amdgcn_global_load_lds(                                            \
                (AS1 const void*)(Bb + (size_t)(h) * 128 * GK + geoff[i] + (tile) * BK), \
                (AS3 void*)(smem + ((tile) & 1) * 65536 + 32768 + (h) * 16384 + ldoff[i]), \
                16, 0, 0);

    auto ldsA = [&](int p, int mh, int mi, int kk) -> const bf16x8* {
        return (const bf16x8*)(smem + p * 65536 + wr * 16384
            + (mh * 64 + mi * 16 + l16) * 128 + (((kk * 4 + quad) ^ bq) * 16));
    };
    auto ldsB = [&](int p, int nh, int ni, int kk) -> const bf16x8* {
        return (const bf16x8*)(smem + p * 65536 + 32768 + (wc >> 1) * 16384
            + ((wc & 1) * 64 + nh * 32 + ni * 16 + l16) * 128 + (((kk * 4 + quad) ^ bq) * 16));
    };

    auto group = [&](int tile) {
        const int p = tile & 1;
        const bool stA = (tile + 1) < NKT;
        const bool stB = (tile + 2) < NKT;
        bf16x8 af[4][2], b0[2][2], b1[2][2];

        // ---------------- P1: (mh0, nh0) ----------------
        #pragma unroll
        for (int mi = 0; mi < 4; ++mi)
            #pragma unroll
            for (int kk = 0; kk < 2; ++kk)
                af[mi][kk] = *ldsA(p, 0, mi, kk);
        #pragma unroll
        for (int ni = 0; ni < 2; ++ni)
            #pragma unroll
            for (int kk = 0; kk < 2; ++kk)
                b0[ni][kk] = *ldsB(p, 0, ni, kk);
        if (stA) { STG_A(tile + 1, 0) }
        BAR;
        __builtin_amdgcn_s_setprio(1);
        #pragma unroll
        for (int kk = 0; kk < 2; ++kk)
            #pragma unroll
            for (int mi = 0; mi < 4; ++mi)
                #pragma unroll
                for (int ni = 0; ni < 2; ++ni)
                    acc[mi][ni] = __builtin_amdgcn_mfma_f32_16x16x32_bf16(af[mi][kk], b0[ni][kk], acc[mi][ni], 0, 0, 0);
        __builtin_amdgcn_s_setprio(0);
        BAR;

        // ---------------- P2: (mh0, nh1) ----------------
        #pragma unroll
        for (int ni = 0; ni < 2; ++ni)
            #pragma unroll
            for (int kk = 0; kk < 2; ++kk)
                b1[ni][kk] = *ldsB(p, 1, ni, kk);
        if (stA) { STG_A(tile + 1, 1) }
        BAR;
        __builtin_amdgcn_s_setprio(1);
        #pragma unroll
        for (int kk = 0; kk < 2; ++kk)
            #pragma unroll
            for (int mi = 0; mi < 4; ++mi)
                #pragma unroll
                for (int ni = 0; ni < 2; ++ni)
                    acc[mi][2 + ni] = __builtin_amdgcn_mfma_f32_16x16x32_bf16(af[mi][kk], b1[ni][kk], acc[mi][2 + ni], 0, 0, 0);
        __builtin_amdgcn_s_setprio(0);
        BAR;

        // ---------------- P3: (mh1, nh1) ----------------
        #pragma unroll
        for (int mi = 0; mi < 4; ++mi)
            #pragma unroll
            for (int kk = 0; kk < 2; ++kk)
                af[mi][kk] = *ldsA(p, 1, mi, kk);
        if (stB) { STG_B(tile + 2, 0) }
        BAR;
        __builtin_amdgcn_s_setprio(1);
        #pragma unroll
        for (int kk = 0; kk < 2; ++kk)
            #pragma unroll
            for (int mi = 0; mi < 4; ++mi)
                #pragma unroll
                for (int ni = 0; ni < 2; ++ni)
                    acc[4 + mi][2 + ni] = __builtin_amdgcn_mfma_f32_16x16x32_bf16(af[mi][kk], b1[ni][kk], acc[4 + mi][2 + ni], 0, 0, 0);
        __builtin_amdgcn_s_setprio(0);
        BAR;

        // ---------------- P4: (mh1, nh0) ----------------
        if (stB) { STG_B(tile + 2, 1) }
        BAR;
        __builtin_amdgcn_s_setprio(1);
        #pragma unroll
        for (int kk = 0; kk < 2; ++kk)
            #pragma unroll
            for (int mi = 0; mi < 4; ++mi)
                #pragma unroll
                for (int ni = 0; ni < 2; ++ni)
                    acc[4 + mi][ni] = __builtin_amdgcn_mfma_f32_16x16x32_bf16(af[mi][kk], b0[ni][kk], acc[4 + mi][ni], 0, 0, 0);
        __builtin_amdgcn_s_setprio(0);
        if (stB) { asm volatile("s_waitcnt vmcnt(4)" ::: "memory"); }
        else     { asm volatile("s_waitcnt vmcnt(0)" ::: "memory"); }
        BAR;
    };

    // prologue
    STG_A(0, 0) STG_A(0, 1) STG_B(0, 0) STG_B(0, 1) STG_B(1, 0) STG_B(1, 1)
    asm volatile("s_waitcnt vmcnt(4)" ::: "memory");
    BAR;

    #pragma unroll 1
    for (int j = 0; j < NKT / 2; ++j) {
        group(2 * j);
        group(2 * j + 1);
    }

    // ---- epilogue: acc -> LDS f32 (one 128-row half at a time) -> stores ----
    const float scale = o.scale;
    float* Cs = (float*)smem;
    #pragma unroll 1
    for (int mh = 0; mh < 2; ++mh) {
        __syncthreads();
        if (wr == mh) {
            #pragma unroll
            for (int mi = 0; mi < 8; ++mi)
                #pragma unroll
                for (int ni = 0; ni < 4; ++ni) {
                    const int col = wc * 64 + ni * 16 + l16;
                    const int jc = col >> 2, cw = col & 3;
                    #pragma unroll
                    for (int r2 = 0; r2 < 4; ++r2) {
                        const int row = mi * 16 + quad * 4 + r2;   // C/D: col=lane&15, row=quad*4+reg
                        Cs[row * 256 + ((jc ^ (row & 15)) << 2) + cw] = acc[mi][ni][r2];
                    }
                }
        }
        __syncthreads();

        if constexpr (__is_same(OutT, u16)) {
            if (o.transp) {
                // store C^T: rows j (N-dim), cols = this half's M rows. 8 iters x us8.
                #pragma unroll
                for (int i = 0; i < 8; ++i) {
                    const int c = t + 512 * i;
                    const int j = c >> 4, seg = c & 15;
                    const int jc = j >> 2, cw = j & 3;
                    float v[8];
                    #pragma unroll
                    for (int k = 0; k < 8; ++k) {
                        const int row = seg * 8 + k;               // 0..127 within half
                        v[k] = Cs[row * 256 + ((jc ^ (row & 15)) << 2) + cw] * scale;
                    }
                    const int grow2 = bx * BN + j;                 // N-dim row of C^T
                    const int gcol2 = by * BM + mh * 128 + seg * 8;// M-dim col of C^T
                    if (o.resF) {
                        const float* rp = o.resF + ((size_t)bz << 20) + (size_t)grow2 * 1024 + gcol2;
                        float4 f1 = *(const float4*)(rp);
                        float4 f2 = *(const float4*)(rp + 4);
                        v[0] += f1.x; v[1] += f1.y; v[2] += f1.z; v[3] += f1.w;
                        v[4] += f2.x; v[5] += f2.y; v[6] += f2.z; v[7] += f2.w;
                    }
                    us8 ov;
                    #pragma unroll
                    for (int k = 0; k < 8; ++k) ov[k] = f2b(v[k]);
                    *(us8*)((u16*)o.C + (size_t)bz * o.sC + (size_t)grow2 * GN + gcol2) = ov;
                }
            } else {
                #pragma unroll
                for (int i = 0; i < 8; ++i) {
                    const int c = t + 512 * i;
                    const int lr = c >> 5, cc = c & 31;
                    const int sxy = lr & 15;
                    const float* s0 = Cs + lr * 256 + (((cc * 2) ^ sxy) << 2);
                    const float* s1 = Cs + lr * 256 + (((cc * 2 + 1) ^ sxy) << 2);
                    float4 a = *(const float4*)s0;
                    float4 b = *(const float4*)s1;
                    const int grow = by * BM + mh * 128 + lr;
                    const int gcol = bx * BN + cc * 8;
                    const float br = (o.biasMode == 1) ? o.bias[grow] : 0.0f;
                    float v[8] = {a.x, a.y, a.z, a.w, b.x, b.y, b.z, b.w};
                    #pragma unroll
                    for (int jj = 0; jj < 8; ++jj) v[jj] = v[jj] * scale + br;
                    if (o.biasMode == 2) {
                        float4 c1 = *(const float4*)(o.bias + gcol);
                        float4 c2 = *(const float4*)(o.bias + gcol + 4);
                        v[0] += c1.x; v[1] += c1.y; v[2] += c1.z; v[3] += c1.w;
                        v[4] += c2.x; v[5] += c2.y; v[6] += c2.z; v[7] += c2.w;
                    }
                    if (o.r1u) {
                        const float u = o.r1u[grow];
                        float4 c1 = *(const float4*)(o.r1v + gcol);
                        float4 c2 = *(const float4*)(o.r1v + gcol + 4);
                        v[0] += u * c1.x; v[1] += u * c1.y; v[2] += u * c1.z; v[3] += u * c1.w;
                        v[4] += u * c2.x; v[5] += u * c2.y; v[6] += u * c2.z; v[7] += u * c2.w;
                    }
                    if (o.res) {
                        us8 rv = *(const us8*)(o.res + (size_t)bz * o.sR + (size_t)grow * GN + gcol);
                        #pragma unroll
                        for (int jj = 0; jj < 8; ++jj) v[jj] += b2f(rv[jj]);
                    }
                    us8 ov;
                    #pragma unroll
                    for (int jj = 0; jj < 8; ++jj) ov[jj] = f2b(v[jj]);
                    *(us8*)((u16*)o.C + (size_t)bz * o.sC + (size_t)grow * GN + gcol) = ov;
                }
            }
        } else {
            #pragma unroll
            for (int i = 0; i < 16; ++i) {
                const int c = t + 512 * i;
                const int lr = c >> 6, cc4 = c & 63;
                const float* src = Cs + lr * 256 + ((cc4 ^ (lr & 15)) << 2);
                float4 a = *(const float4*)src;
                const int grow = by * BM + mh * 128 + lr;
                const int gcol = bx * BN + cc4 * 4;
                const float br = (o.biasMode == 1) ? o.bias[grow] : 0.0f;
                float v[4] = {a.x, a.y, a.z, a.w};
                #pragma unroll
                for (int jj = 0; jj < 4; ++jj) v[jj] = v[jj] * scale + br;
                if (o.biasMode == 2) {
                    float4 c1 = *(const float4*)(o.bias + gcol);
                    v[0] += c1.x; v[1] += c1.y; v[2] += c1.z; v[3] += c1.w;
                }
                if (o.r1u) {
                    const float u = o.r1u[grow];
                    float4 c1 = *(const float4*)(o.r1v + gcol);
                    v[0] += u * c1.x; v[1] += u * c1.y; v[2] += u * c1.z; v[3] += u * c1.w;
                }
                if (o.res) {
                    ushort4 rv = *(const ushort4*)(o.res + (size_t)bz * o.sR + (size_t)grow * GN + gcol);
                    v[0] += b2f(rv.x); v[1] += b2f(rv.y); v[2] += b2f(rv.z); v[3] += b2f(rv.w);
                }
                float4 ov = {v[0], v[1], v[2], v[3]};
                *(float4*)((float*)o.C + (size_t)bz * o.sC + (size_t)grow * GN + gcol) = ov;
            }
        }
    }
    #undef STG_A
    #undef STG_B
}

// in-place row softmax over 1024-wide bf16 rows, fp32 math
__global__ __launch_bounds__(256) void softmax_rows(u16* __restrict__ S)
{
    const size_t row = blockIdx.x;
    u16* p = S + row * 1024;
    const int t = threadIdx.x;
    ushort4 u = ((const ushort4*)p)[t];
    float v0 = b2f(u.x), v1 = b2f(u.y), v2 = b2f(u.z), v3 = b2f(u.w);

    float m = fmaxf(fmaxf(v0, v1), fmaxf(v2, v3));
    #pragma unroll
    for (int o = 32; o > 0; o >>= 1) m = fmaxf(m, __shfl_xor(m, o, 64));
    __shared__ float red[8];
    const int wave = t >> 6, lane = t & 63;
    if (lane == 0) red[wave] = m;
    __syncthreads();
    m = fmaxf(fmaxf(red[0], red[1]), fmaxf(red[2], red[3]));

    v0 = __expf(v0 - m); v1 = __expf(v1 - m); v2 = __expf(v2 - m); v3 = __expf(v3 - m);
    float s = v0 + v1 + v2 + v3;
    #pragma unroll
    for (int o = 32; o > 0; o >>= 1) s += __shfl_xor(s, o, 64);
    if (lane == 0) red[4 + wave] = s;
    __syncthreads();
    s = red[4] + red[5] + red[6] + red[7];
    const float inv = 1.0f / s;

    u.x = f2b(v0 * inv); u.y = f2b(v1 * inv); u.z = f2b(v2 * inv); u.w = f2b(v3 * inv);
    ((ushort4*)p)[t] = u;
}

// out[b](1024x1024 bf16) = transpose of in[b](1024x1024 fp32), fused convert
__global__ __launch_bounds__(256) void tconv_k(const float* __restrict__ in, u16* __restrict__ out)
{
    __shared__ float tile[64][65];
    const size_t base = (size_t)blockIdx.z * 1024 * 1024;
    const float* ib = in + base;
    u16* ob = out + base;
    const int t = threadIdx.x;
    const int vc = t & 15;
    const int rr0 = t >> 4;
    const int tr = blockIdx.y * 64, tc = blockIdx.x * 64;

    #pragma unroll
    for (int rr = 0; rr < 4; ++rr) {
        const int row = rr * 16 + rr0;
        float4 u = *(const float4*)(ib + (size_t)(tr + row) * 1024 + tc + vc * 4);
        tile[row][vc * 4 + 0] = u.x; tile[row][vc * 4 + 1] = u.y;
        tile[row][vc * 4 + 2] = u.z; tile[row][vc * 4 + 3] = u.w;
    }
    __syncthreads();
    #pragma unroll
    for (int rr = 0; rr < 4; ++rr) {
        const int orow = rr * 16 + rr0;
        ushort4 u;
        u.x = f2b(tile[vc * 4 + 0][orow]); u.y = f2b(tile[vc * 4 + 1][orow]);
        u.z = f2b(tile[vc * 4 + 2][orow]); u.w = f2b(tile[vc * 4 + 3][orow]);
        *(ushort4*)(ob + (size_t)(tc + orow) * 1024 + tr + vc * 4) = u;
    }
}

// convert 8 fp32 1024x1024 weight matrices to bf16
struct WPack { const float* in[8]; u16* out[8]; };
__global__ __launch_bounds__(256) void convw_k(WPack p)
{
    const int m = blockIdx.y;
    const int i = (blockIdx.x * 256 + threadIdx.x) * 4;
    float4 v = *(const float4*)(p.in[m] + i);
    ushort4 s;
    s.x = f2b(v.x); s.y = f2b(v.y); s.z = f2b(v.z); s.w = f2b(v.w);
    *(ushort4*)(p.out[m] + i) = s;
}

// s[m] = sum_n w[m][n]  (fp32 row sums of 1024x1024)
__global__ __launch_bounds__(256) void rowsum_k(const float* __restrict__ w, float* __restrict__ s)
{
    const int m = blockIdx.x;
    const float* r = w + (size_t)m * 1024;
    const int t = threadIdx.x;
    float4 v = ((const float4*)r)[t];
    float x = v.x + v.y + v.z + v.w;
    #pragma unroll
    for (int o = 32; o > 0; o >>= 1) x += __shfl_xor(x, o, 64);
    __shared__ float red[4];
    if ((t & 63) == 0) red[t >> 6] = x;
    __syncthreads();
    if (t == 0) s[m] = red[0] + red[1] + red[2] + red[3];
}

static inline GOp mkop(const u16* A, long long sA, const u16* B, long long sB,
                       void* C, long long sC,
                       const float* bias, int bm, const u16* res, long long sR,
                       float sc, const float* r1u, const float* r1v,
                       const float* resF, int tr)
{
    GOp o;
    o.A = A; o.B = B; o.C = C;
    o.sA = sA; o.sB = sB; o.sC = sC; o.sR = sR;
    o.bias = bias; o.res = res; o.r1u = r1u; o.r1v = r1v; o.resF = resF;
    o.scale = sc; o.biasMode = bm; o.transp = tr;
    return o;
}

extern "C" void kernel_launch(void* const* d_in, const int* in_sizes, int n_in,
                              void* d_out, int out_size, void* d_ws, size_t ws_size,
                              hipStream_t stream) {
    const size_t mat = (size_t)32 * 1024 * 1024;   // elems per batched (32,1024,1024) buffer
    const long long mm = 1024LL * 1024LL;          // per-batch stride
    const float sc = 1.0f / 32.0f;                 // 1/sqrt(1024)

    const float* x  = (const float*)d_in[0];
    const float* w1 = (const float*)d_in[1];  const float* b1 = (const float*)d_in[2];
    const float* w2 = (const float*)d_in[3];  const float* b2 = (const float*)d_in[4];
    const float* w3 = (const float*)d_in[5];  const float* b3 = (const float*)d_in[6];
    const float* w4 = (const float*)d_in[7];  const float* b4 = (const float*)d_in[8];
    const float* w5 = (const float*)d_in[9];  const float* b5 = (const float*)d_in[10];
    const float* w6 = (const float*)d_in[11]; const float* b6 = (const float*)d_in[12];
    const float* w7 = (const float*)d_in[13]; const float* b7 = (const float*)d_in[14];
    const float* wl = (const float*)d_in[15]; const float* bl = (const float*)d_in[16];
    float* out = (float*)d_out;

    u16* Axt = (u16*)d_ws;
    u16* Bv = Axt + mat;
    u16* Cv = Axt + 2 * mat;
    u16* Dv = Axt + 3 * mat;
    u16* wb = Axt + 4 * mat;
    u16 *w1b = wb, *w2b = wb + (1<<20), *w3b = wb + 2*(1<<20), *w4b = wb + 3*(1<<20),
        *w5b = wb + 4*(1<<20), *w6b = wb + 5*(1<<20), *w7b = wb + 6*(1<<20), *wlb = wb + 7*(1<<20);
    float* swl = (float*)(wb + 8*(1<<20));   // 1024 fp32 row-sums of wl
    u16* OutLo = (u16*)d_out;
    u16* OutHi = OutLo + mat;

    WPack wp;
    wp.in[0]=w1; wp.in[1]=w2; wp.in[2]=w3; wp.in[3]=w4; wp.in[4]=w5; wp.in[5]=w6; wp.in[6]=w7; wp.in[7]=wl;
    wp.out[0]=w1b; wp.out[1]=w2b; wp.out[2]=w3b; wp.out[3]=w4b; wp.out[4]=w5b; wp.out[5]=w6b; wp.out[6]=w7b; wp.out[7]=wlb;

    const dim3 blk(256);
    const dim3 blkG(512);
    const dim3 gG(512);
    const dim3 gT(16, 16, 32), gS(32 * 1024), gW(1024, 8), gR(1024);
    const float* NUL = nullptr;
    const u16* NUS = nullptr;

    convw_k<<<gW, blk, 0, stream>>>(wp);
    rowsum_k<<<gR, blk, 0, stream>>>(wl, swl);
    tconv_k<<<gT, blk, 0, stream>>>(x, Axt);                                  // Axt = x^T (b,n,c)

    // --- attention block 1 ---
    gemm_nt<u16><<<gG, blkG, 0, stream>>>(
        mkop(Axt, mm, w1b, 0, Bv, mm, b1, 2, NUS, 0, 1.0f, NUL, NUL, NUL, 0));     // B = Q1t
    gemm_nt<u16><<<gG, blkG, 0, stream>>>(
        mkop(Axt, mm, w2b, 0, Cv, mm, b2, 2, NUS, 0, 1.0f, NUL, NUL, NUL, 0));     // C = K1t
    gemm_nt<u16><<<gG, blkG, 0, stream>>>(
        mkop(w3b, 0, Axt, mm, Dv, mm, b3, 1, NUS, 0, 1.0f, NUL, NUL, NUL, 0));     // D = V1
    gemm_nt<u16><<<gG, blkG, 0, stream>>>(
        mkop(Bv, mm, Cv, mm, OutLo, mm, NUL, 0, NUS, 0, sc, NUL, NUL, NUL, 0));    // S1
    softmax_rows<<<gS, blk, 0, stream>>>(OutLo);                                   // A1
    // X1 natural = (A1 V1^T)^T + x  (transposed epilogue, fp32 residual)
    gemm_nt<u16><<<gG, blkG, 0, stream>>>(
        mkop(OutLo, mm, Dv, mm, Axt, mm, NUL, 0, NUS, 0, 1.0f, NUL, NUL, x, 1));   // Axt = X1

    // --- attention block 2 via commuted lin/conv: Z = X1·wl^T ---
    gemm_nt<u16><<<gG, blkG, 0, stream>>>(
        mkop(wlb, 0, Axt, mm, Cv, mm, NUL, 0, NUS, 0, 1.0f, NUL, NUL, NUL, 0));    // C = Zt
    gemm_nt<u16><<<gG, blkG, 0, stream>>>(
        mkop(Cv, mm, w5b, 0, Dv, mm, bl, 1, NUS, 0, 1.0f, swl, b5, NUL, 0));       // D = Q2t
    gemm_nt<u16><<<gG, blkG, 0, stream>>>(
        mkop(Cv, mm, w6b, 0, OutLo, mm, bl, 1, NUS, 0, 1.0f, swl, b6, NUL, 0));    // OutLo = K2t
    gemm_nt<u16><<<gG, blkG, 0, stream>>>(
        mkop(w7b, 0, Cv, mm, OutHi, mm, bl, 2, NUS, 0, 1.0f, b7, swl, NUL, 0));    // OutHi = V2
    gemm_nt<u16><<<gG, blkG, 0, stream>>>(
        mkop(Dv, mm, OutLo, mm, Bv, mm, NUL, 0, NUS, 0, sc, NUL, NUL, NUL, 0));    // B = S2
    softmax_rows<<<gS, blk, 0, stream>>>(Bv);                                      // A2
    gemm_nt<u16><<<gG, blkG, 0, stream>>>(
        mkop(Bv, mm, OutHi, mm, Cv, mm, NUL, 0, NUS, 0, 1.0f, NUL, NUL, NUL, 0));  // C = O2t
    gemm_nt<float><<<gG, blkG, 0, stream>>>(
        mkop(w4b, 0, Cv, mm, out, mm, b4, 1, Axt, mm, 1.0f, NUL, NUL, NUL, 0));    // out = w4 O2 + b4 + X1
}

// Round 6
// 1343.109 us; speedup vs baseline: 2.0271x; 2.0271x over previous
//
#include <hip/hip_runtime.h>
#include <hip/hip_bf16.h>
#include <cstdint>

typedef unsigned short u16;
typedef __bf16 bf16x8 __attribute__((ext_vector_type(8)));
typedef float f32x4 __attribute__((ext_vector_type(4)));
typedef unsigned short us8 __attribute__((ext_vector_type(8)));

#define AS1 __attribute__((address_space(1)))
#define AS3 __attribute__((address_space(3)))

__device__ __forceinline__ float b2f(u16 u) {
    union { float f; uint32_t i; } c; c.i = ((uint32_t)u) << 16; return c.f;
}
__device__ __forceinline__ u16 f2b(float f) {
    union { float f; uint32_t i; } c; c.f = f;
    return (u16)((c.i + 0x7fffu + ((c.i >> 16) & 1u)) >> 16);
}

#define BM 256
#define BN 256
#define BK 64
#define GK 1024
#define GN 1024
#define NKT (GK / BK)   // 16 K-tiles

#define BAR asm volatile("s_barrier" ::: "memory")

// C[b] (MxN row-major) = scale*(A[b] @ B[b]^T) [+bias(row|col) fp32]
//                        [+r1u[row]*r1v[col] rank-1 fp32] [+res(bf16)]
// A: MxK row-major bf16, B: NxK row-major bf16. M=N=K=1024.
//
// 256x256 tile, BK=64, 8 waves (2Mx4N), 512 threads, 128 KiB LDS (2 bufs).
// 8-phase schedule with counted vmcnt; raw s_barrier keeps staging loads in
// flight across barriers. LDS 16B chunks XOR-swizzled.
template <typename OutT>
__global__ __launch_bounds__(512, 2) void gemm_nt(
    const u16* __restrict__ A, long long sA,
    const u16* __restrict__ B, long long sB,
    OutT* __restrict__ C, long long sC,
    const float* __restrict__ bias, int biasMode,   // 0 none, 1 row, 2 col
    const u16* __restrict__ res, long long sR,
    float scale,
    const float* __restrict__ r1u, const float* __restrict__ r1v)
{
    __shared__ __align__(16) char smem[131072];

    const int t = threadIdx.x;
    // XCD-aware bijective swizzle: 512 blocks, 64 consecutive per XCD
    const int orig = blockIdx.x;
    const int id2 = (orig & 7) * 64 + (orig >> 3);
    const int bz = id2 >> 4;           // batch 0..31
    const int by = (id2 >> 2) & 3;     // M tile 0..3
    const int bx = id2 & 3;            // N tile 0..3

    const u16* Ab = A + (size_t)bz * sA + (size_t)(by * BM) * GK;
    const u16* Bb = B + (size_t)bz * sB + (size_t)(bx * BN) * GK;

    const int wave = t >> 6, lane = t & 63;
    const int l16 = lane & 15, quad = lane >> 4;
    const int wr = wave >> 2;      // 0..1  (M: 128 rows each)
    const int wc = wave & 3;       // 0..3  (N: 64 cols each)
    const int bq = l16 & 7;

    f32x4 acc[8][4] = {};

    int geoff[2], ldoff[2];
    #pragma unroll
    for (int i = 0; i < 2; ++i) {
        const int c = t + 512 * i;
        const int r = c >> 3, js = c & 7;
        geoff[i] = r * GK + (js ^ (r & 7)) * 8;
        ldoff[i] = c * 16;
    }

    #define STG_A(tile, h)                                                               \
        _Pragma("unroll")                                                                \
        for (int i = 0; i < 2; ++i)                                                      \
            __builtin_amdgcn_global_load_lds(                                            \
                (AS1 const void*)(Ab + (size_t)(h) * 128 * GK + geoff[i] + (tile) * BK), \
                (AS3 void*)(smem + ((tile) & 1) * 65536 + (h) * 16384 + ldoff[i]),       \
                16, 0, 0);
    #define STG_B(tile, h)                                                               \
        _Pragma("unroll")                                                                \
        for (int i = 0; i < 2; ++i)                                                      \
            __builtin_amdgcn_global_load_lds(                                            \
                (AS1 const void*)(Bb + (size_t)(h) * 128 * GK + geoff[i] + (tile) * BK), \
                (AS3 void*)(smem + ((tile) & 1) * 65536 + 32768 + (h) * 16384 + ldoff[i]), \
                16, 0, 0);

    auto ldsA = [&](int p, int mh, int mi, int kk) -> const bf16x8* {
        return (const bf16x8*)(smem + p * 65536 + wr * 16384
            + (mh * 64 + mi * 16 + l16) * 128 + (((kk * 4 + quad) ^ bq) * 16));
    };
    auto ldsB = [&](int p, int nh, int ni, int kk) -> const bf16x8* {
        return (const bf16x8*)(smem + p * 65536 + 32768 + (wc >> 1) * 16384
            + ((wc & 1) * 64 + nh * 32 + ni * 16 + l16) * 128 + (((kk * 4 + quad) ^ bq) * 16));
    };

    auto group = [&](int tile) {
        const int p = tile & 1;
        const bool stA = (tile + 1) < NKT;
        const bool stB = (tile + 2) < NKT;
        bf16x8 af[4][2], b0[2][2], b1[2][2];

        // ---------------- P1: (mh0, nh0) ----------------
        #pragma unroll
        for (int mi = 0; mi < 4; ++mi)
            #pragma unroll
            for (int kk = 0; kk < 2; ++kk)
                af[mi][kk] = *ldsA(p, 0, mi, kk);
        #pragma unroll
        for (int ni = 0; ni < 2; ++ni)
            #pragma unroll
            for (int kk = 0; kk < 2; ++kk)
                b0[ni][kk] = *ldsB(p, 0, ni, kk);
        if (stA) { STG_A(tile + 1, 0) }
        BAR;
        __builtin_amdgcn_s_setprio(1);
        #pragma unroll
        for (int kk = 0; kk < 2; ++kk)
            #pragma unroll
            for (int mi = 0; mi < 4; ++mi)
                #pragma unroll
                for (int ni = 0; ni < 2; ++ni)
                    acc[mi][ni] = __builtin_amdgcn_mfma_f32_16x16x32_bf16(af[mi][kk], b0[ni][kk], acc[mi][ni], 0, 0, 0);
        __builtin_amdgcn_s_setprio(0);
        BAR;

        // ---------------- P2: (mh0, nh1) ----------------
        #pragma unroll
        for (int ni = 0; ni < 2; ++ni)
            #pragma unroll
            for (int kk = 0; kk < 2; ++kk)
                b1[ni][kk] = *ldsB(p, 1, ni, kk);
        if (stA) { STG_A(tile + 1, 1) }
        BAR;
        __builtin_amdgcn_s_setprio(1);
        #pragma unroll
        for (int kk = 0; kk < 2; ++kk)
            #pragma unroll
            for (int mi = 0; mi < 4; ++mi)
                #pragma unroll
                for (int ni = 0; ni < 2; ++ni)
                    acc[mi][2 + ni] = __builtin_amdgcn_mfma_f32_16x16x32_bf16(af[mi][kk], b1[ni][kk], acc[mi][2 + ni], 0, 0, 0);
        __builtin_amdgcn_s_setprio(0);
        BAR;

        // ---------------- P3: (mh1, nh1) ----------------
        #pragma unroll
        for (int mi = 0; mi < 4; ++mi)
            #pragma unroll
            for (int kk = 0; kk < 2; ++kk)
                af[mi][kk] = *ldsA(p, 1, mi, kk);
        if (stB) { STG_B(tile + 2, 0) }
        BAR;
        __builtin_amdgcn_s_setprio(1);
        #pragma unroll
        for (int kk = 0; kk < 2; ++kk)
            #pragma unroll
            for (int mi = 0; mi < 4; ++mi)
                #pragma unroll
                for (int ni = 0; ni < 2; ++ni)
                    acc[4 + mi][2 + ni] = __builtin_amdgcn_mfma_f32_16x16x32_bf16(af[mi][kk], b1[ni][kk], acc[4 + mi][2 + ni], 0, 0, 0);
        __builtin_amdgcn_s_setprio(0);
        BAR;

        // ---------------- P4: (mh1, nh0) ----------------
        if (stB) { STG_B(tile + 2, 1) }
        BAR;
        __builtin_amdgcn_s_setprio(1);
        #pragma unroll
        for (int kk = 0; kk < 2; ++kk)
            #pragma unroll
            for (int mi = 0; mi < 4; ++mi)
                #pragma unroll
                for (int ni = 0; ni < 2; ++ni)
                    acc[4 + mi][ni] = __builtin_amdgcn_mfma_f32_16x16x32_bf16(af[mi][kk], b0[ni][kk], acc[4 + mi][ni], 0, 0, 0);
        __builtin_amdgcn_s_setprio(0);
        if (stB) { asm volatile("s_waitcnt vmcnt(4)" ::: "memory"); }
        else     { asm volatile("s_waitcnt vmcnt(0)" ::: "memory"); }
        BAR;
    };

    // prologue: A(0) both halves, B(0) both halves, B(1) both halves
    STG_A(0, 0) STG_A(0, 1) STG_B(0, 0) STG_B(0, 1) STG_B(1, 0) STG_B(1, 1)
    asm volatile("s_waitcnt vmcnt(4)" ::: "memory");
    BAR;

    #pragma unroll 1
    for (int j = 0; j < NKT / 2; ++j) {
        group(2 * j);
        group(2 * j + 1);
    }

    // ---- epilogue: acc -> LDS f32 (one 128-row half at a time) -> coalesced stores ----
    float* Cs = (float*)smem;
    #pragma unroll
    for (int mh = 0; mh < 2; ++mh) {
        __syncthreads();
        if (wr == mh) {
            #pragma unroll
            for (int mi = 0; mi < 8; ++mi)
                #pragma unroll
                for (int ni = 0; ni < 4; ++ni) {
                    const int col = wc * 64 + ni * 16 + l16;
                    const int jc = col >> 2, cw = col & 3;
                    #pragma unroll
                    for (int r2 = 0; r2 < 4; ++r2) {
                        const int row = mi * 16 + quad * 4 + r2;   // C/D: col=lane&15, row=quad*4+reg
                        Cs[row * 256 + ((jc ^ (row & 15)) << 2) + cw] = acc[mi][ni][r2];
                    }
                }
        }
        __syncthreads();

        if constexpr (__is_same(OutT, u16)) {
            #pragma unroll
            for (int i = 0; i < 8; ++i) {
                const int c = t + 512 * i;
                const int lr = c >> 5, cc = c & 31;
                const int sxy = lr & 15;
                const float* s0 = Cs + lr * 256 + (((cc * 2) ^ sxy) << 2);
                const float* s1 = Cs + lr * 256 + (((cc * 2 + 1) ^ sxy) << 2);
                float4 a = *(const float4*)s0;
                float4 b = *(const float4*)s1;
                const int grow = by * BM + mh * 128 + lr;
                const int gcol = bx * BN + cc * 8;
                const float br = (biasMode == 1) ? bias[grow] : 0.0f;
                float v[8] = {a.x, a.y, a.z, a.w, b.x, b.y, b.z, b.w};
                #pragma unroll
                for (int jj = 0; jj < 8; ++jj) v[jj] = v[jj] * scale + br;
                if (biasMode == 2) {
                    float4 c1 = *(const float4*)(bias + gcol);
                    float4 c2 = *(const float4*)(bias + gcol + 4);
                    v[0] += c1.x; v[1] += c1.y; v[2] += c1.z; v[3] += c1.w;
                    v[4] += c2.x; v[5] += c2.y; v[6] += c2.z; v[7] += c2.w;
                }
                if (r1u) {
                    const float u = r1u[grow];
                    float4 c1 = *(const float4*)(r1v + gcol);
                    float4 c2 = *(const float4*)(r1v + gcol + 4);
                    v[0] += u * c1.x; v[1] += u * c1.y; v[2] += u * c1.z; v[3] += u * c1.w;
                    v[4] += u * c2.x; v[5] += u * c2.y; v[6] += u * c2.z; v[7] += u * c2.w;
                }
                if (res) {
                    us8 rv = *(const us8*)(res + (size_t)bz * sR + (size_t)grow * GN + gcol);
                    #pragma unroll
                    for (int jj = 0; jj < 8; ++jj) v[jj] += b2f(rv[jj]);
                }
                us8 o;
                #pragma unroll
                for (int jj = 0; jj < 8; ++jj) o[jj] = f2b(v[jj]);
                *(us8*)((u16*)C + (size_t)bz * sC + (size_t)grow * GN + gcol) = o;
            }
        } else {
            #pragma unroll
            for (int i = 0; i < 16; ++i) {
                const int c = t + 512 * i;
                const int lr = c >> 6, cc4 = c & 63;
                const float* src = Cs + lr * 256 + ((cc4 ^ (lr & 15)) << 2);
                float4 a = *(const float4*)src;
                const int grow = by * BM + mh * 128 + lr;
                const int gcol = bx * BN + cc4 * 4;
                const float br = (biasMode == 1) ? bias[grow] : 0.0f;
                float v[4] = {a.x, a.y, a.z, a.w};
                #pragma unroll
                for (int jj = 0; jj < 4; ++jj) v[jj] = v[jj] * scale + br;
                if (biasMode == 2) {
                    float4 c1 = *(const float4*)(bias + gcol);
                    v[0] += c1.x; v[1] += c1.y; v[2] += c1.z; v[3] += c1.w;
                }
                if (r1u) {
                    const float u = r1u[grow];
                    float4 c1 = *(const float4*)(r1v + gcol);
                    v[0] += u * c1.x; v[1] += u * c1.y; v[2] += u * c1.z; v[3] += u * c1.w;
                }
                if (res) {
                    ushort4 rv = *(const ushort4*)(res + (size_t)bz * sR + (size_t)grow * GN + gcol);
                    v[0] += b2f(rv.x); v[1] += b2f(rv.y); v[2] += b2f(rv.z); v[3] += b2f(rv.w);
                }
                float4 o = {v[0], v[1], v[2], v[3]};
                *(float4*)((float*)C + (size_t)bz * sC + (size_t)grow * GN + gcol) = o;
            }
        }
    }
    #undef STG_A
    #undef STG_B
}

// in-place row softmax over 1024-wide bf16 rows, fp32 math
__global__ __launch_bounds__(256) void softmax_rows(u16* __restrict__ S)
{
    const size_t row = blockIdx.x;
    u16* p = S + row * 1024;
    const int t = threadIdx.x;
    ushort4 u = ((const ushort4*)p)[t];
    float v0 = b2f(u.x), v1 = b2f(u.y), v2 = b2f(u.z), v3 = b2f(u.w);

    float m = fmaxf(fmaxf(v0, v1), fmaxf(v2, v3));
    #pragma unroll
    for (int o = 32; o > 0; o >>= 1) m = fmaxf(m, __shfl_xor(m, o, 64));
    __shared__ float red[8];
    const int wave = t >> 6, lane = t & 63;
    if (lane == 0) red[wave] = m;
    __syncthreads();
    m = fmaxf(fmaxf(red[0], red[1]), fmaxf(red[2], red[3]));

    v0 = __expf(v0 - m); v1 = __expf(v1 - m); v2 = __expf(v2 - m); v3 = __expf(v3 - m);
    float s = v0 + v1 + v2 + v3;
    #pragma unroll
    for (int o = 32; o > 0; o >>= 1) s += __shfl_xor(s, o, 64);
    if (lane == 0) red[4 + wave] = s;
    __syncthreads();
    s = red[4] + red[5] + red[6] + red[7];
    const float inv = 1.0f / s;

    u.x = f2b(v0 * inv); u.y = f2b(v1 * inv); u.z = f2b(v2 * inv); u.w = f2b(v3 * inv);
    ((ushort4*)p)[t] = u;
}

// out[b](1024x1024 bf16) = transpose of in[b](1024x1024 bf16)
__global__ __launch_bounds__(256) void transpose_k(const u16* __restrict__ in, u16* __restrict__ out)
{
    __shared__ u16 tile[64][65];
    const size_t base = (size_t)blockIdx.z * 1024 * 1024;
    const u16* ib = in + base;
    u16* ob = out + base;
    const int t = threadIdx.x;
    const int vc = t & 15;
    const int rr0 = t >> 4;
    const int tr = blockIdx.y * 64, tc = blockIdx.x * 64;

    #pragma unroll
    for (int rr = 0; rr < 4; ++rr) {
        const int row = rr * 16 + rr0;
        ushort4 u = *(const ushort4*)(ib + (size_t)(tr + row) * 1024 + tc + vc * 4);
        tile[row][vc * 4 + 0] = u.x; tile[row][vc * 4 + 1] = u.y;
        tile[row][vc * 4 + 2] = u.z; tile[row][vc * 4 + 3] = u.w;
    }
    __syncthreads();
    #pragma unroll
    for (int rr = 0; rr < 4; ++rr) {
        const int orow = rr * 16 + rr0;
        ushort4 u;
        u.x = tile[vc * 4 + 0][orow]; u.y = tile[vc * 4 + 1][orow];
        u.z = tile[vc * 4 + 2][orow]; u.w = tile[vc * 4 + 3][orow];
        *(ushort4*)(ob + (size_t)(tc + orow) * 1024 + tr + vc * 4) = u;
    }
}

// out[b](1024x1024 bf16) = transpose of in[b](1024x1024 fp32), fused convert
__global__ __launch_bounds__(256) void tconv_k(const float* __restrict__ in, u16* __restrict__ out)
{
    __shared__ float tile[64][65];
    const size_t base = (size_t)blockIdx.z * 1024 * 1024;
    const float* ib = in + base;
    u16* ob = out + base;
    const int t = threadIdx.x;
    const int vc = t & 15;
    const int rr0 = t >> 4;
    const int tr = blockIdx.y * 64, tc = blockIdx.x * 64;

    #pragma unroll
    for (int rr = 0; rr < 4; ++rr) {
        const int row = rr * 16 + rr0;
        float4 u = *(const float4*)(ib + (size_t)(tr + row) * 1024 + tc + vc * 4);
        tile[row][vc * 4 + 0] = u.x; tile[row][vc * 4 + 1] = u.y;
        tile[row][vc * 4 + 2] = u.z; tile[row][vc * 4 + 3] = u.w;
    }
    __syncthreads();
    #pragma unroll
    for (int rr = 0; rr < 4; ++rr) {
        const int orow = rr * 16 + rr0;
        ushort4 u;
        u.x = f2b(tile[vc * 4 + 0][orow]); u.y = f2b(tile[vc * 4 + 1][orow]);
        u.z = f2b(tile[vc * 4 + 2][orow]); u.w = f2b(tile[vc * 4 + 3][orow]);
        *(ushort4*)(ob + (size_t)(tc + orow) * 1024 + tr + vc * 4) = u;
    }
}

// convert 8 fp32 1024x1024 weight matrices to bf16
struct WPack { const float* in[8]; u16* out[8]; };
__global__ __launch_bounds__(256) void convw_k(WPack p)
{
    const int m = blockIdx.y;
    const int i = (blockIdx.x * 256 + threadIdx.x) * 4;
    float4 v = *(const float4*)(p.in[m] + i);
    ushort4 s;
    s.x = f2b(v.x); s.y = f2b(v.y); s.z = f2b(v.z); s.w = f2b(v.w);
    *(ushort4*)(p.out[m] + i) = s;
}

// s[m] = sum_n w[m][n]  (fp32 row sums of 1024x1024)
__global__ __launch_bounds__(256) void rowsum_k(const float* __restrict__ w, float* __restrict__ s)
{
    const int m = blockIdx.x;
    const float* r = w + (size_t)m * 1024;
    const int t = threadIdx.x;
    float4 v = ((const float4*)r)[t];
    float x = v.x + v.y + v.z + v.w;
    #pragma unroll
    for (int o = 32; o > 0; o >>= 1) x += __shfl_xor(x, o, 64);
    __shared__ float red[4];
    if ((t & 63) == 0) red[t >> 6] = x;
    __syncthreads();
    if (t == 0) s[m] = red[0] + red[1] + red[2] + red[3];
}

extern "C" void kernel_launch(void* const* d_in, const int* in_sizes, int n_in,
                              void* d_out, int out_size, void* d_ws, size_t ws_size,
                              hipStream_t stream) {
    const size_t mat = (size_t)32 * 1024 * 1024;   // elems per batched (32,1024,1024) buffer
    const long long mm = 1024LL * 1024LL;          // per-batch stride
    const float sc = 1.0f / 32.0f;                 // 1/sqrt(1024)

    const float* x  = (const float*)d_in[0];
    const float* w1 = (const float*)d_in[1];  const float* b1 = (const float*)d_in[2];
    const float* w2 = (const float*)d_in[3];  const float* b2 = (const float*)d_in[4];
    const float* w3 = (const float*)d_in[5];  const float* b3 = (const float*)d_in[6];
    const float* w4 = (const float*)d_in[7];  const float* b4 = (const float*)d_in[8];
    const float* w5 = (const float*)d_in[9];  const float* b5 = (const float*)d_in[10];
    const float* w6 = (const float*)d_in[11]; const float* b6 = (const float*)d_in[12];
    const float* w7 = (const float*)d_in[13]; const float* b7 = (const float*)d_in[14];
    const float* wl = (const float*)d_in[15]; const float* bl = (const float*)d_in[16];
    float* out = (float*)d_out;

    u16* A = (u16*)d_ws;
    u16* Bv = A + mat;
    u16* Cv = A + 2 * mat;
    u16* Dv = A + 3 * mat;
    u16* wb = A + 4 * mat;
    u16 *w1b = wb, *w2b = wb + (1<<20), *w3b = wb + 2*(1<<20), *w4b = wb + 3*(1<<20),
        *w5b = wb + 4*(1<<20), *w6b = wb + 5*(1<<20), *w7b = wb + 6*(1<<20), *wlb = wb + 7*(1<<20);
    float* swl = (float*)(wb + 8*(1<<20));   // 1024 fp32 row-sums of wl
    u16* OutLo = (u16*)d_out;
    u16* OutHi = OutLo + mat;

    WPack wp;
    wp.in[0]=w1; wp.in[1]=w2; wp.in[2]=w3; wp.in[3]=w4; wp.in[4]=w5; wp.in[5]=w6; wp.in[6]=w7; wp.in[7]=wl;
    wp.out[0]=w1b; wp.out[1]=w2b; wp.out[2]=w3b; wp.out[3]=w4b; wp.out[4]=w5b; wp.out[5]=w6b; wp.out[6]=w7b; wp.out[7]=wlb;

    const dim3 blk(256);
    const dim3 blkG(512);
    const dim3 gG(512);
    const dim3 gT(16, 16, 32), gS(32 * 1024), gW(1024, 8), gR(1024);
    const float* NUL = nullptr;

    convw_k<<<gW, blk, 0, stream>>>(wp);
    rowsum_k<<<gR, blk, 0, stream>>>(wl, swl);                                                   // swl = rowsum(wl)
    tconv_k<<<gT, blk, 0, stream>>>(x, A);                                                       // A = x^T (b,n,c)

    // --- attention block 1 ---
    gemm_nt<u16><<<gG, blkG, 0, stream>>>(A, mm, w1b, 0, Bv, mm, b1, 2, nullptr, 0, 1.0f, NUL, NUL);  // B = Q1t
    gemm_nt<u16><<<gG, blkG, 0, stream>>>(A, mm, w2b, 0, Cv, mm, b2, 2, nullptr, 0, 1.0f, NUL, NUL);  // C = K1t
    gemm_nt<u16><<<gG, blkG, 0, stream>>>(w3b, 0, A, mm, Dv, mm, b3, 1, nullptr, 0, 1.0f, NUL, NUL);  // D = V1
    gemm_nt<u16><<<gG, blkG, 0, stream>>>(Bv, mm, Cv, mm, OutLo, mm, nullptr, 0, nullptr, 0, sc, NUL, NUL); // S1
    softmax_rows<<<gS, blk, 0, stream>>>(OutLo);                                                 // A1
    gemm_nt<u16><<<gG, blkG, 0, stream>>>(OutLo, mm, Dv, mm, Bv, mm, nullptr, 0, A, mm, 1.0f, NUL, NUL);  // B = X1t
    transpose_k<<<gT, blk, 0, stream>>>(Bv, A);                                                  // A = X1 natural

    // --- attention block 2 via commuted lin/conv:
    //     lin(conv_i(X1)) = w_i · (X1·wl^T) + b_i ⊗ swl + bl,  Z = X1·wl^T ---
    gemm_nt<u16><<<gG, blkG, 0, stream>>>(wlb, 0, A, mm, Cv, mm, nullptr, 0, nullptr, 0, 1.0f, NUL, NUL); // C = Zt (m,c)
    gemm_nt<u16><<<gG, blkG, 0, stream>>>(Cv, mm, w5b, 0, Dv, mm, bl, 1, nullptr, 0, 1.0f, swl, b5);      // D = Q2t (m,d)
    gemm_nt<u16><<<gG, blkG, 0, stream>>>(Cv, mm, w6b, 0, OutLo, mm, bl, 1, nullptr, 0, 1.0f, swl, b6);   // OutLo = K2t (m,d)
    gemm_nt<u16><<<gG, blkG, 0, stream>>>(w7b, 0, Cv, mm, OutHi, mm, bl, 2, nullptr, 0, 1.0f, b7, swl);   // OutHi = V2 (d,m)
    gemm_nt<u16><<<gG, blkG, 0, stream>>>(Dv, mm, OutLo, mm, Bv, mm, nullptr, 0, nullptr, 0, sc, NUL, NUL); // B = S2
    softmax_rows<<<gS, blk, 0, stream>>>(Bv);                                                    // A2
    gemm_nt<u16><<<gG, blkG, 0, stream>>>(Bv, mm, OutHi, mm, Cv, mm, nullptr, 0, nullptr, 0, 1.0f, NUL, NUL); // C = O2t
    gemm_nt<float><<<gG, blkG, 0, stream>>>(w4b, 0, Cv, mm, out, mm, b4, 1, A, mm, 1.0f, NUL, NUL);      // out = w4 O2 + b4 + X1
}

// Round 7
// 1294.923 us; speedup vs baseline: 2.1025x; 1.0372x over previous
//
#include <hip/hip_runtime.h>
#include <hip/hip_bf16.h>
#include <cstdint>

typedef unsigned short u16;
typedef __bf16 bf16x8 __attribute__((ext_vector_type(8)));
typedef float f32x4 __attribute__((ext_vector_type(4)));
typedef unsigned short us8 __attribute__((ext_vector_type(8)));

#define AS1 __attribute__((address_space(1)))
#define AS3 __attribute__((address_space(3)))

__device__ __forceinline__ float b2f(u16 u) {
    union { float f; uint32_t i; } c; c.i = ((uint32_t)u) << 16; return c.f;
}
__device__ __forceinline__ u16 f2b(float f) {
    union { float f; uint32_t i; } c; c.f = f;
    return (u16)((c.i + 0x7fffu + ((c.i >> 16) & 1u)) >> 16);
}

#define BM 256
#define BN 256
#define BK 64
#define GK 1024
#define GN 1024
#define NKT (GK / BK)   // 16 K-tiles

#define BAR asm volatile("s_barrier" ::: "memory")

// C[b] (MxN row-major) = scale*(A[b] @ B[b]^T) [+bias(row|col) fp32]
//                        [+r1u⊗r1v] [+r2u⊗r2v] [+res(bf16)]
// A: MxK row-major bf16, B: NxK row-major bf16. M=N=K=1024 (or single 1024² with grid 16).
//
// 256x256 tile, BK=64, 8 waves (2Mx4N), 512 threads, 128 KiB LDS (2 bufs).
// 8-phase schedule with counted vmcnt; raw s_barrier keeps staging loads in
// flight across barriers. LDS 16B chunks XOR-swizzled.
// NOTE: one op per dispatch — merging heterogeneous ops thrashed L2/L3 (round 4).
template <typename OutT>
__global__ __launch_bounds__(512, 2) void gemm_nt(
    const u16* __restrict__ A, long long sA,
    const u16* __restrict__ B, long long sB,
    OutT* __restrict__ C, long long sC,
    const float* __restrict__ bias, int biasMode,   // 0 none, 1 row, 2 col
    const u16* __restrict__ res, long long sR,
    float scale,
    const float* __restrict__ r1u, const float* __restrict__ r1v,
    const float* __restrict__ r2u, const float* __restrict__ r2v)
{
    __shared__ __align__(16) char smem[131072];

    const int t = threadIdx.x;
    // XCD-aware bijective swizzle: gridDim.x % 8 == 0; contiguous chunk per XCD
    const int orig = blockIdx.x;
    const int cpx = gridDim.x >> 3;
    const int id2 = (orig & 7) * cpx + (orig >> 3);
    const int bz = id2 >> 4;           // batch
    const int by = (id2 >> 2) & 3;     // M tile 0..3
    const int bx = id2 & 3;            // N tile 0..3

    const u16* Ab = A + (size_t)bz * sA + (size_t)(by * BM) * GK;
    const u16* Bb = B + (size_t)bz * sB + (size_t)(bx * BN) * GK;

    const int wave = t >> 6, lane = t & 63;
    const int l16 = lane & 15, quad = lane >> 4;
    const int wr = wave >> 2;      // 0..1  (M: 128 rows each)
    const int wc = wave & 3;       // 0..3  (N: 64 cols each)
    const int bq = l16 & 7;

    f32x4 acc[8][4] = {};

    int geoff[2], ldoff[2];
    #pragma unroll
    for (int i = 0; i < 2; ++i) {
        const int c = t + 512 * i;
        const int r = c >> 3, js = c & 7;
        geoff[i] = r * GK + (js ^ (r & 7)) * 8;
        ldoff[i] = c * 16;
    }

    #define STG_A(tile, h)                                                               \
        _Pragma("unroll")                                                                \
        for (int i = 0; i < 2; ++i)                                                      \
            __builtin_amdgcn_global_load_lds(                                            \
                (AS1 const void*)(Ab + (size_t)(h) * 128 * GK + geoff[i] + (tile) * BK), \
                (AS3 void*)(smem + ((tile) & 1) * 65536 + (h) * 16384 + ldoff[i]),       \
                16, 0, 0);
    #define STG_B(tile, h)                                                               \
        _Pragma("unroll")                                                                \
        for (int i = 0; i < 2; ++i)                                                      \
            __builtin_amdgcn_global_load_lds(                                            \
                (AS1 const void*)(Bb + (size_t)(h) * 128 * GK + geoff[i] + (tile) * BK), \
                (AS3 void*)(smem + ((tile) & 1) * 65536 + 32768 + (h) * 16384 + ldoff[i]), \
                16, 0, 0);

    auto ldsA = [&](int p, int mh, int mi, int kk) -> const bf16x8* {
        return (const bf16x8*)(smem + p * 65536 + wr * 16384
            + (mh * 64 + mi * 16 + l16) * 128 + (((kk * 4 + quad) ^ bq) * 16));
    };
    auto ldsB = [&](int p, int nh, int ni, int kk) -> const bf16x8* {
        return (const bf16x8*)(smem + p * 65536 + 32768 + (wc >> 1) * 16384
            + ((wc & 1) * 64 + nh * 32 + ni * 16 + l16) * 128 + (((kk * 4 + quad) ^ bq) * 16));
    };

    auto group = [&](int tile) {
        const int p = tile & 1;
        const bool stA = (tile + 1) < NKT;
        const bool stB = (tile + 2) < NKT;
        bf16x8 af[4][2], b0[2][2], b1[2][2];

        // ---------------- P1: (mh0, nh0) ----------------
        #pragma unroll
        for (int mi = 0; mi < 4; ++mi)
            #pragma unroll
            for (int kk = 0; kk < 2; ++kk)
                af[mi][kk] = *ldsA(p, 0, mi, kk);
        #pragma unroll
        for (int ni = 0; ni < 2; ++ni)
            #pragma unroll
            for (int kk = 0; kk < 2; ++kk)
                b0[ni][kk] = *ldsB(p, 0, ni, kk);
        if (stA) { STG_A(tile + 1, 0) }
        BAR;
        __builtin_amdgcn_s_setprio(1);
        #pragma unroll
        for (int kk = 0; kk < 2; ++kk)
            #pragma unroll
            for (int mi = 0; mi < 4; ++mi)
                #pragma unroll
                for (int ni = 0; ni < 2; ++ni)
                    acc[mi][ni] = __builtin_amdgcn_mfma_f32_16x16x32_bf16(af[mi][kk], b0[ni][kk], acc[mi][ni], 0, 0, 0);
        __builtin_amdgcn_s_setprio(0);
        BAR;

        // ---------------- P2: (mh0, nh1) ----------------
        #pragma unroll
        for (int ni = 0; ni < 2; ++ni)
            #pragma unroll
            for (int kk = 0; kk < 2; ++kk)
                b1[ni][kk] = *ldsB(p, 1, ni, kk);
        if (stA) { STG_A(tile + 1, 1) }
        BAR;
        __builtin_amdgcn_s_setprio(1);
        #pragma unroll
        for (int kk = 0; kk < 2; ++kk)
            #pragma unroll
            for (int mi = 0; mi < 4; ++mi)
                #pragma unroll
                for (int ni = 0; ni < 2; ++ni)
                    acc[mi][2 + ni] = __builtin_amdgcn_mfma_f32_16x16x32_bf16(af[mi][kk], b1[ni][kk], acc[mi][2 + ni], 0, 0, 0);
        __builtin_amdgcn_s_setprio(0);
        BAR;

        // ---------------- P3: (mh1, nh1) ----------------
        #pragma unroll
        for (int mi = 0; mi < 4; ++mi)
            #pragma unroll
            for (int kk = 0; kk < 2; ++kk)
                af[mi][kk] = *ldsA(p, 1, mi, kk);
        if (stB) { STG_B(tile + 2, 0) }
        BAR;
        __builtin_amdgcn_s_setprio(1);
        #pragma unroll
        for (int kk = 0; kk < 2; ++kk)
            #pragma unroll
            for (int mi = 0; mi < 4; ++mi)
                #pragma unroll
                for (int ni = 0; ni < 2; ++ni)
                    acc[4 + mi][2 + ni] = __builtin_amdgcn_mfma_f32_16x16x32_bf16(af[mi][kk], b1[ni][kk], acc[4 + mi][2 + ni], 0, 0, 0);
        __builtin_amdgcn_s_setprio(0);
        BAR;

        // ---------------- P4: (mh1, nh0) ----------------
        if (stB) { STG_B(tile + 2, 1) }
        BAR;
        __builtin_amdgcn_s_setprio(1);
        #pragma unroll
        for (int kk = 0; kk < 2; ++kk)
            #pragma unroll
            for (int mi = 0; mi < 4; ++mi)
                #pragma unroll
                for (int ni = 0; ni < 2; ++ni)
                    acc[4 + mi][ni] = __builtin_amdgcn_mfma_f32_16x16x32_bf16(af[mi][kk], b0[ni][kk], acc[4 + mi][ni], 0, 0, 0);
        __builtin_amdgcn_s_setprio(0);
        if (stB) { asm volatile("s_waitcnt vmcnt(4)" ::: "memory"); }
        else     { asm volatile("s_waitcnt vmcnt(0)" ::: "memory"); }
        BAR;
    };

    // prologue: A(0) both halves, B(0) both halves, B(1) both halves
    STG_A(0, 0) STG_A(0, 1) STG_B(0, 0) STG_B(0, 1) STG_B(1, 0) STG_B(1, 1)
    asm volatile("s_waitcnt vmcnt(4)" ::: "memory");
    BAR;

    #pragma unroll 1
    for (int j = 0; j < NKT / 2; ++j) {
        group(2 * j);
        group(2 * j + 1);
    }

    // ---- epilogue: acc -> LDS f32 (one 128-row half at a time) -> coalesced stores ----
    float* Cs = (float*)smem;
    #pragma unroll
    for (int mh = 0; mh < 2; ++mh) {
        __syncthreads();
        if (wr == mh) {
            #pragma unroll
            for (int mi = 0; mi < 8; ++mi)
                #pragma unroll
                for (int ni = 0; ni < 4; ++ni) {
                    const int col = wc * 64 + ni * 16 + l16;
                    const int jc = col >> 2, cw = col & 3;
                    #pragma unroll
                    for (int r2 = 0; r2 < 4; ++r2) {
                        const int row = mi * 16 + quad * 4 + r2;   // C/D: col=lane&15, row=quad*4+reg
                        Cs[row * 256 + ((jc ^ (row & 15)) << 2) + cw] = acc[mi][ni][r2];
                    }
                }
        }
        __syncthreads();

        if constexpr (__is_same(OutT, u16)) {
            #pragma unroll
            for (int i = 0; i < 8; ++i) {
                const int c = t + 512 * i;
                const int lr = c >> 5, cc = c & 31;
                const int sxy = lr & 15;
                const float* s0 = Cs + lr * 256 + (((cc * 2) ^ sxy) << 2);
                const float* s1 = Cs + lr * 256 + (((cc * 2 + 1) ^ sxy) << 2);
                float4 a = *(const float4*)s0;
                float4 b = *(const float4*)s1;
                const int grow = by * BM + mh * 128 + lr;
                const int gcol = bx * BN + cc * 8;
                const float br = (biasMode == 1) ? bias[grow] : 0.0f;
                float v[8] = {a.x, a.y, a.z, a.w, b.x, b.y, b.z, b.w};
                #pragma unroll
                for (int jj = 0; jj < 8; ++jj) v[jj] = v[jj] * scale + br;
                if (biasMode == 2) {
                    float4 c1 = *(const float4*)(bias + gcol);
                    float4 c2 = *(const float4*)(bias + gcol + 4);
                    v[0] += c1.x; v[1] += c1.y; v[2] += c1.z; v[3] += c1.w;
                    v[4] += c2.x; v[5] += c2.y; v[6] += c2.z; v[7] += c2.w;
                }
                if (r1u) {
                    const float u = r1u[grow];
                    float4 c1 = *(const float4*)(r1v + gcol);
                    float4 c2 = *(const float4*)(r1v + gcol + 4);
                    v[0] += u * c1.x; v[1] += u * c1.y; v[2] += u * c1.z; v[3] += u * c1.w;
                    v[4] += u * c2.x; v[5] += u * c2.y; v[6] += u * c2.z; v[7] += u * c2.w;
                }
                if (r2u) {
                    const float u = r2u[grow];
                    float4 c1 = *(const float4*)(r2v + gcol);
                    float4 c2 = *(const float4*)(r2v + gcol + 4);
                    v[0] += u * c1.x; v[1] += u * c1.y; v[2] += u * c1.z; v[3] += u * c1.w;
                    v[4] += u * c2.x; v[5] += u * c2.y; v[6] += u * c2.z; v[7] += u * c2.w;
                }
                if (res) {
                    us8 rv = *(const us8*)(res + (size_t)bz * sR + (size_t)grow * GN + gcol);
                    #pragma unroll
                    for (int jj = 0; jj < 8; ++jj) v[jj] += b2f(rv[jj]);
                }
                us8 o;
                #pragma unroll
                for (int jj = 0; jj < 8; ++jj) o[jj] = f2b(v[jj]);
                *(us8*)((u16*)C + (size_t)bz * sC + (size_t)grow * GN + gcol) = o;
            }
        } else {
            #pragma unroll
            for (int i = 0; i < 16; ++i) {
                const int c = t + 512 * i;
                const int lr = c >> 6, cc4 = c & 63;
                const float* src = Cs + lr * 256 + ((cc4 ^ (lr & 15)) << 2);
                float4 a = *(const float4*)src;
                const int grow = by * BM + mh * 128 + lr;
                const int gcol = bx * BN + cc4 * 4;
                const float br = (biasMode == 1) ? bias[grow] : 0.0f;
                float v[4] = {a.x, a.y, a.z, a.w};
                #pragma unroll
                for (int jj = 0; jj < 4; ++jj) v[jj] = v[jj] * scale + br;
                if (biasMode == 2) {
                    float4 c1 = *(const float4*)(bias + gcol);
                    v[0] += c1.x; v[1] += c1.y; v[2] += c1.z; v[3] += c1.w;
                }
                if (r1u) {
                    const float u = r1u[grow];
                    float4 c1 = *(const float4*)(r1v + gcol);
                    v[0] += u * c1.x; v[1] += u * c1.y; v[2] += u * c1.z; v[3] += u * c1.w;
                }
                if (r2u) {
                    const float u = r2u[grow];
                    float4 c1 = *(const float4*)(r2v + gcol);
                    v[0] += u * c1.x; v[1] += u * c1.y; v[2] += u * c1.z; v[3] += u * c1.w;
                }
                if (res) {
                    ushort4 rv = *(const ushort4*)(res + (size_t)bz * sR + (size_t)grow * GN + gcol);
                    v[0] += b2f(rv.x); v[1] += b2f(rv.y); v[2] += b2f(rv.z); v[3] += b2f(rv.w);
                }
                float4 o = {v[0], v[1], v[2], v[3]};
                *(float4*)((float*)C + (size_t)bz * sC + (size_t)grow * GN + gcol) = o;
            }
        }
    }
    #undef STG_A
    #undef STG_B
}

// in-place row softmax over 1024-wide bf16 rows, fp32 math
__global__ __launch_bounds__(256) void softmax_rows(u16* __restrict__ S)
{
    const size_t row = blockIdx.x;
    u16* p = S + row * 1024;
    const int t = threadIdx.x;
    ushort4 u = ((const ushort4*)p)[t];
    float v0 = b2f(u.x), v1 = b2f(u.y), v2 = b2f(u.z), v3 = b2f(u.w);

    float m = fmaxf(fmaxf(v0, v1), fmaxf(v2, v3));
    #pragma unroll
    for (int o = 32; o > 0; o >>= 1) m = fmaxf(m, __shfl_xor(m, o, 64));
    __shared__ float red[8];
    const int wave = t >> 6, lane = t & 63;
    if (lane == 0) red[wave] = m;
    __syncthreads();
    m = fmaxf(fmaxf(red[0], red[1]), fmaxf(red[2], red[3]));

    v0 = __expf(v0 - m); v1 = __expf(v1 - m); v2 = __expf(v2 - m); v3 = __expf(v3 - m);
    float s = v0 + v1 + v2 + v3;
    #pragma unroll
    for (int o = 32; o > 0; o >>= 1) s += __shfl_xor(s, o, 64);
    if (lane == 0) red[4 + wave] = s;
    __syncthreads();
    s = red[4] + red[5] + red[6] + red[7];
    const float inv = 1.0f / s;

    u.x = f2b(v0 * inv); u.y = f2b(v1 * inv); u.z = f2b(v2 * inv); u.w = f2b(v3 * inv);
    ((ushort4*)p)[t] = u;
}

// out[b](1024x1024 bf16) = transpose of in[b](1024x1024 bf16)
__global__ __launch_bounds__(256) void transpose_k(const u16* __restrict__ in, u16* __restrict__ out)
{
    __shared__ u16 tile[64][65];
    const size_t base = (size_t)blockIdx.z * 1024 * 1024;
    const u16* ib = in + base;
    u16* ob = out + base;
    const int t = threadIdx.x;
    const int vc = t & 15;
    const int rr0 = t >> 4;
    const int tr = blockIdx.y * 64, tc = blockIdx.x * 64;

    #pragma unroll
    for (int rr = 0; rr < 4; ++rr) {
        const int row = rr * 16 + rr0;
        ushort4 u = *(const ushort4*)(ib + (size_t)(tr + row) * 1024 + tc + vc * 4);
        tile[row][vc * 4 + 0] = u.x; tile[row][vc * 4 + 1] = u.y;
        tile[row][vc * 4 + 2] = u.z; tile[row][vc * 4 + 3] = u.w;
    }
    __syncthreads();
    #pragma unroll
    for (int rr = 0; rr < 4; ++rr) {
        const int orow = rr * 16 + rr0;
        ushort4 u;
        u.x = tile[vc * 4 + 0][orow]; u.y = tile[vc * 4 + 1][orow];
        u.z = tile[vc * 4 + 2][orow]; u.w = tile[vc * 4 + 3][orow];
        *(ushort4*)(ob + (size_t)(tc + orow) * 1024 + tr + vc * 4) = u;
    }
}

// out[b](1024x1024 bf16) = transpose of in[b](1024x1024 fp32), fused convert
__global__ __launch_bounds__(256) void tconv_k(const float* __restrict__ in, u16* __restrict__ out)
{
    __shared__ float tile[64][65];
    const size_t base = (size_t)blockIdx.z * 1024 * 1024;
    const float* ib = in + base;
    u16* ob = out + base;
    const int t = threadIdx.x;
    const int vc = t & 15;
    const int rr0 = t >> 4;
    const int tr = blockIdx.y * 64, tc = blockIdx.x * 64;

    #pragma unroll
    for (int rr = 0; rr < 4; ++rr) {
        const int row = rr * 16 + rr0;
        float4 u = *(const float4*)(ib + (size_t)(tr + row) * 1024 + tc + vc * 4);
        tile[row][vc * 4 + 0] = u.x; tile[row][vc * 4 + 1] = u.y;
        tile[row][vc * 4 + 2] = u.z; tile[row][vc * 4 + 3] = u.w;
    }
    __syncthreads();
    #pragma unroll
    for (int rr = 0; rr < 4; ++rr) {
        const int orow = rr * 16 + rr0;
        ushort4 u;
        u.x = f2b(tile[vc * 4 + 0][orow]); u.y = f2b(tile[vc * 4 + 1][orow]);
        u.z = f2b(tile[vc * 4 + 2][orow]); u.w = f2b(tile[vc * 4 + 3][orow]);
        *(ushort4*)(ob + (size_t)(tc + orow) * 1024 + tr + vc * 4) = u;
    }
}

// convert 8 fp32 1024x1024 weight matrices to bf16
struct WPack { const float* in[8]; u16* out[8]; };
__global__ __launch_bounds__(256) void convw_k(WPack p)
{
    const int m = blockIdx.y;
    const int i = (blockIdx.x * 256 + threadIdx.x) * 4;
    float4 v = *(const float4*)(p.in[m] + i);
    ushort4 s;
    s.x = f2b(v.x); s.y = f2b(v.y); s.z = f2b(v.z); s.w = f2b(v.w);
    *(ushort4*)(p.out[m] + i) = s;
}

// s[m] = sum_n w[m][n]  (fp32 row sums of 1024x1024)
__global__ __launch_bounds__(256) void rowsum_k(const float* __restrict__ w, float* __restrict__ s)
{
    const int m = blockIdx.x;
    const float* r = w + (size_t)m * 1024;
    const int t = threadIdx.x;
    float4 v = ((const float4*)r)[t];
    float x = v.x + v.y + v.z + v.w;
    #pragma unroll
    for (int o = 32; o > 0; o >>= 1) x += __shfl_xor(x, o, 64);
    __shared__ float red[4];
    if ((t & 63) == 0) red[t >> 6] = x;
    __syncthreads();
    if (t == 0) s[m] = red[0] + red[1] + red[2] + red[3];
}

// outv[m] = dot(w[m,:], vvec)  (fp32 1024x1024 matvec)
__global__ __launch_bounds__(256) void matvec_k(const float* __restrict__ w,
                                                const float* __restrict__ vvec,
                                                float* __restrict__ outv)
{
    const int m = blockIdx.x;
    const float* r = w + (size_t)m * 1024;
    const int t = threadIdx.x;
    float4 a = ((const float4*)r)[t];
    float4 b = ((const float4*)vvec)[t];
    float x = a.x * b.x + a.y * b.y + a.z * b.z + a.w * b.w;
    #pragma unroll
    for (int o = 32; o > 0; o >>= 1) x += __shfl_xor(x, o, 64);
    __shared__ float red[4];
    if ((t & 63) == 0) red[t >> 6] = x;
    __syncthreads();
    if (t == 0) outv[m] = red[0] + red[1] + red[2] + red[3];
}

extern "C" void kernel_launch(void* const* d_in, const int* in_sizes, int n_in,
                              void* d_out, int out_size, void* d_ws, size_t ws_size,
                              hipStream_t stream) {
    const size_t mat = (size_t)32 * 1024 * 1024;   // elems per batched (32,1024,1024) buffer
    const long long mm = 1024LL * 1024LL;          // per-batch stride
    const float sc = 1.0f / 32.0f;                 // 1/sqrt(1024)

    const float* x  = (const float*)d_in[0];
    const float* w1 = (const float*)d_in[1];  const float* b1 = (const float*)d_in[2];
    const float* w2 = (const float*)d_in[3];  const float* b2 = (const float*)d_in[4];
    const float* w3 = (const float*)d_in[5];  const float* b3 = (const float*)d_in[6];
    const float* w4 = (const float*)d_in[7];  const float* b4 = (const float*)d_in[8];
    const float* w5 = (const float*)d_in[9];  const float* b5 = (const float*)d_in[10];
    const float* w6 = (const float*)d_in[11]; const float* b6 = (const float*)d_in[12];
    const float* w7 = (const float*)d_in[13]; const float* b7 = (const float*)d_in[14];
    const float* wl = (const float*)d_in[15]; const float* bl = (const float*)d_in[16];
    float* out = (float*)d_out;

    u16* A = (u16*)d_ws;
    u16* Bv = A + mat;
    u16* Cv = A + 2 * mat;
    u16* Dv = A + 3 * mat;
    u16* wb = A + 4 * mat;
    u16 *w1b = wb, *w2b = wb + (1<<20), *w3b = wb + 2*(1<<20), *w4b = wb + 3*(1<<20),
        *w5b = wb + 4*(1<<20), *w6b = wb + 5*(1<<20), *w7b = wb + 6*(1<<20), *wlb = wb + 7*(1<<20);
    u16* extra = wb + 8 * (1<<20);
    float* swl   = (float*)extra;            // 1024 fp32 rowsum(wl)
    float* sw4   = swl + 1024;               // 1024 fp32 rowsum(w4)
    float* w4b7v = swl + 2048;               // 1024 fp32 w4 @ b7
    u16* w7tb = extra + 8192;                // 1024x1024 bf16 w7^T
    u16* W47b = w7tb + (1<<20);              // 1024x1024 bf16 w4 @ w7
    u16* OutLo = (u16*)d_out;                // scratch inside d_out (overwritten by final)

    WPack wp;
    wp.in[0]=w1; wp.in[1]=w2; wp.in[2]=w3; wp.in[3]=w4; wp.in[4]=w5; wp.in[5]=w6; wp.in[6]=w7; wp.in[7]=wl;
    wp.out[0]=w1b; wp.out[1]=w2b; wp.out[2]=w3b; wp.out[3]=w4b; wp.out[4]=w5b; wp.out[5]=w6b; wp.out[6]=w7b; wp.out[7]=wlb;

    const dim3 blk(256);
    const dim3 blkG(512);
    const dim3 gG(512), gG1(16);
    const dim3 gT(16, 16, 32), gT1(16, 16, 1), gS(32 * 1024), gW(1024, 8), gR(1024);
    const float* NUL = nullptr;

    convw_k<<<gW, blk, 0, stream>>>(wp);
    rowsum_k<<<gR, blk, 0, stream>>>(wl, swl);                                   // swl = rowsum(wl)
    rowsum_k<<<gR, blk, 0, stream>>>(w4, sw4);                                   // sw4 = rowsum(w4)
    matvec_k<<<gR, blk, 0, stream>>>(w4, b7, w4b7v);                             // w4b7v = w4 @ b7
    transpose_k<<<gT1, blk, 0, stream>>>(w7b, w7tb);                             // w7tb = w7^T
    // W47 = w4 @ w7 (single 1024^3, grid 16)
    gemm_nt<u16><<<gG1, blkG, 0, stream>>>(w4b, 0, w7tb, 0, W47b, 0,
        NUL, 0, nullptr, 0, 1.0f, NUL, NUL, NUL, NUL);
    tconv_k<<<gT, blk, 0, stream>>>(x, A);                                       // A = x^T (b,n,c)

    // --- attention block 1 ---
    gemm_nt<u16><<<gG, blkG, 0, stream>>>(A, mm, w1b, 0, Bv, mm, b1, 2, nullptr, 0, 1.0f, NUL, NUL, NUL, NUL);  // B = Q1t
    gemm_nt<u16><<<gG, blkG, 0, stream>>>(A, mm, w2b, 0, Cv, mm, b2, 2, nullptr, 0, 1.0f, NUL, NUL, NUL, NUL);  // C = K1t
    gemm_nt<u16><<<gG, blkG, 0, stream>>>(w3b, 0, A, mm, Dv, mm, b3, 1, nullptr, 0, 1.0f, NUL, NUL, NUL, NUL);  // D = V1
    gemm_nt<u16><<<gG, blkG, 0, stream>>>(Bv, mm, Cv, mm, OutLo, mm, NUL, 0, nullptr, 0, sc, NUL, NUL, NUL, NUL); // S1
    softmax_rows<<<gS, blk, 0, stream>>>(OutLo);                                 // A1
    gemm_nt<u16><<<gG, blkG, 0, stream>>>(OutLo, mm, Dv, mm, Bv, mm, NUL, 0, A, mm, 1.0f, NUL, NUL, NUL, NUL);  // B = X1t
    transpose_k<<<gT, blk, 0, stream>>>(Bv, A);                                  // A = X1 natural

    // --- attention block 2 via commuted lin/conv: Z = X1·wl^T ---
    gemm_nt<u16><<<gG, blkG, 0, stream>>>(wlb, 0, A, mm, Cv, mm, NUL, 0, nullptr, 0, 1.0f, NUL, NUL, NUL, NUL); // C = Zt (m,c)
    gemm_nt<u16><<<gG, blkG, 0, stream>>>(Cv, mm, w5b, 0, Dv, mm, bl, 1, nullptr, 0, 1.0f, swl, b5, NUL, NUL);  // D = Q2t
    gemm_nt<u16><<<gG, blkG, 0, stream>>>(Cv, mm, w6b, 0, OutLo, mm, bl, 1, nullptr, 0, 1.0f, swl, b6, NUL, NUL); // OutLo = K2t
    gemm_nt<u16><<<gG, blkG, 0, stream>>>(Dv, mm, OutLo, mm, Bv, mm, NUL, 0, nullptr, 0, sc, NUL, NUL, NUL, NUL); // B = S2
    softmax_rows<<<gS, blk, 0, stream>>>(Bv);                                    // A2
    // W4V2[b] = W47 @ Zt[b]^T + sw4⊗bl + w4b7⊗swl   (folds V2- and O2t-chains)
    gemm_nt<u16><<<gG, blkG, 0, stream>>>(W47b, 0, Cv, mm, Dv, mm, NUL, 0, nullptr, 0, 1.0f, sw4, bl, w4b7v, swl); // D = W4V2 (d,m)
    // out[b] = W4V2[b] @ A2[b]^T + b4 + X1
    gemm_nt<float><<<gG, blkG, 0, stream>>>(Dv, mm, Bv, mm, out, mm, b4, 1, A, mm, 1.0f, NUL, NUL, NUL, NUL);
}